// Round 12
// baseline (179.269 us; speedup 1.0000x reference)
//
#include <hip/hip_runtime.h>
#include <hip/hip_bf16.h>

// GraphQNetwork: 2x GCNConv (9->32->64, relu) + global mean pool + station MLP.
// Round 25: r24 with P3/P4 UN-merged. Differencing r20/r21/r24 shows the
// P3+P4 merge itself triggers scratch spill at the 64-VGPR allocator ceiling
// (r20 no-merge: 32KB writes; r24 merge: 18.5MB) — the saved barrier cost more
// in spill than it saved in sync. Kept from r24 (verified good): sort2 blob
// offload, (i+t)&15 zero ordering, 520B Ms/Buf strides (conflicts 9.65M ->
// 1.72M). 7 barriers/graph. Partition kernels unchanged.

#define NNODES 262144
#define NPG 256
#define NGRAPHS 1024
#define NEDGES 2097152
#define NFEAT 9
#define ECAP2 2560
#define T_EDGES 8192
#define NTILES (NEDGES / T_EDGES)   // 256
#define TPB 1024
#define NBLK 256
#define EBSTRIDE 4608               // per-graph blob stride: El@0, dinvs@2560, Rl@3584
#define MROW 520                    // Ms row stride (bytes): 512 data + 8 pad
#define BROW 520                    // Buf row stride

typedef __hip_bfloat16 bf16;
typedef short short8 __attribute__((ext_vector_type(8)));
typedef float f32x4 __attribute__((ext_vector_type(4)));

__device__ __forceinline__ float bfbits(unsigned short u) { return __uint_as_float(((unsigned)u) << 16); }
__device__ __forceinline__ unsigned short f2bbits(float v) { bf16 b = __float2bfloat16(v); return *(unsigned short*)&b; }

// ---- edge partition: deterministic counting sort, no global atomics --------

__global__ void __launch_bounds__(1024) k_hist(const int* __restrict__ dst,
                                               int* __restrict__ hist) {
    __shared__ int cnt[NGRAPHS];
    int t = threadIdx.x;
    cnt[t] = 0;
    __syncthreads();
    const int4* d4 = (const int4*)(dst + blockIdx.x * T_EDGES);
#pragma unroll
    for (int k = 0; k < T_EDGES / 4096; ++k) {
        int4 dv = d4[k * 1024 + t];
        atomicAdd(&cnt[dv.x >> 8], 1);
        atomicAdd(&cnt[dv.y >> 8], 1);
        atomicAdd(&cnt[dv.z >> 8], 1);
        atomicAdd(&cnt[dv.w >> 8], 1);
    }
    __syncthreads();
    hist[blockIdx.x * NGRAPHS + t] = cnt[t];
}

__global__ void __launch_bounds__(256) k_scan(int* __restrict__ hist,
                                              int* __restrict__ gcnt) {
    __shared__ int wsum[4];
    int g = blockIdx.x;
    int t = threadIdx.x;            // tile index
    int lane = t & 63, wv = t >> 6;
    int v = hist[t * NGRAPHS + g];
    int inc = v;
    for (int off = 1; off < 64; off <<= 1) {
        int y = __shfl_up(inc, off);
        if (lane >= off) inc += y;
    }
    if (lane == 63) wsum[wv] = inc;
    __syncthreads();
    int wpre = 0;
#pragma unroll
    for (int w = 0; w < 3; ++w) if (w < wv) wpre += wsum[w];
    int exc = wpre + inc - v;
    hist[t * NGRAPHS + g] = exc;
    if (t == 255) gcnt[g * 16] = exc + v;
}

__global__ void __launch_bounds__(1024) k_scatter(const int* __restrict__ src,
                                                  const int* __restrict__ dst,
                                                  const int* __restrict__ hist,
                                                  unsigned short* __restrict__ gout) {
    __shared__ unsigned short sg[T_EDGES];
    __shared__ unsigned short pay[T_EDGES];
    __shared__ unsigned short spay[T_EDGES];
    __shared__ unsigned short ssg[T_EDGES];
    __shared__ int cnt[NGRAPHS];
    __shared__ int lbase[NGRAPHS];
    __shared__ int gb[NGRAPHS];
    __shared__ int wsum[16];
    int t = threadIdx.x;
    int lane = t & 63, wv = t >> 6;
    int base = blockIdx.x * T_EDGES;
    cnt[t] = 0;
    gb[t] = hist[blockIdx.x * NGRAPHS + t];
    __syncthreads();
    const int4* s4 = (const int4*)(src + base);
    const int4* d4 = (const int4*)(dst + base);
#pragma unroll
    for (int k = 0; k < T_EDGES / 4096; ++k) {
        int idx = k * 1024 + t;
        int4 dv = d4[idx];
        int4 sv = s4[idx];
        int i0 = idx * 4;
        sg[i0]     = (unsigned short)(dv.x >> 8);
        sg[i0 + 1] = (unsigned short)(dv.y >> 8);
        sg[i0 + 2] = (unsigned short)(dv.z >> 8);
        sg[i0 + 3] = (unsigned short)(dv.w >> 8);
        pay[i0]     = (unsigned short)(((dv.x & 255) << 8) | (sv.x & 255));
        pay[i0 + 1] = (unsigned short)(((dv.y & 255) << 8) | (sv.y & 255));
        pay[i0 + 2] = (unsigned short)(((dv.z & 255) << 8) | (sv.z & 255));
        pay[i0 + 3] = (unsigned short)(((dv.w & 255) << 8) | (sv.w & 255));
        atomicAdd(&cnt[dv.x >> 8], 1);
        atomicAdd(&cnt[dv.y >> 8], 1);
        atomicAdd(&cnt[dv.z >> 8], 1);
        atomicAdd(&cnt[dv.w >> 8], 1);
    }
    __syncthreads();
    int c = cnt[t];
    int inc = c;
    for (int off = 1; off < 64; off <<= 1) {
        int y = __shfl_up(inc, off);
        if (lane >= off) inc += y;
    }
    if (lane == 63) wsum[wv] = inc;
    __syncthreads();
    int wpre = 0;
    for (int w = 0; w < wv; ++w) wpre += wsum[w];
    lbase[t] = wpre + inc - c;
    cnt[t] = 0;
    __syncthreads();
#pragma unroll
    for (int k = 0; k < T_EDGES / 1024; ++k) {
        int i = k * 1024 + t;
        int g = sg[i];
        int p = lbase[g] + atomicAdd(&cnt[g], 1);
        spay[p] = pay[i];
        ssg[p] = (unsigned short)g;
    }
    __syncthreads();
#pragma unroll
    for (int k = 0; k < T_EDGES / 1024; ++k) {
        int p = k * 1024 + t;
        int g = ssg[p];
        int off = gb[g] + (p - lbase[g]);
        if (off < ECAP2) gout[(size_t)g * ECAP2 + off] = spay[p];
    }
}

// D: per-graph dst-sort: El (src sorted by dst), Rl run table, dinvs.
__global__ void __launch_bounds__(256) k_sort2(const int* __restrict__ gcnt,
                                               const unsigned short* __restrict__ gout,
                                               unsigned char* __restrict__ eblob) {
    __shared__ unsigned short ep[ECAP2];
    __shared__ unsigned int cnt[256];
    __shared__ unsigned int base[256];
    __shared__ int wsum[4];
    int g = blockIdx.x;
    int t = threadIdx.x;
    int lane = t & 63, wv = t >> 6;
    int ecnt = min(gcnt[g * 16], ECAP2);
    cnt[t] = 0;
    {
        const uint4* gev = (const uint4*)(gout + (size_t)g * ECAP2);
        uint4* epv = (uint4*)ep;
        for (int i = t; i < ECAP2 / 8; i += 256) epv[i] = gev[i];
    }
    __syncthreads();
    for (int i = t; i < ecnt; i += 256) atomicAdd(&cnt[ep[i] >> 8], 1u);
    __syncthreads();
    int c = (int)cnt[t];
    int inc = c;
    for (int off = 1; off < 64; off <<= 1) {
        int y = __shfl_up(inc, off);
        if (lane >= off) inc += y;
    }
    if (lane == 63) wsum[wv] = inc;
    __syncthreads();
    int wpre = 0;
    for (int w = 0; w < wv; ++w) wpre += wsum[w];
    int exc = wpre + inc - c;
    unsigned char* eb = eblob + (size_t)g * EBSTRIDE;
    ((unsigned short*)(eb + 3584))[t] = (unsigned short)exc;
    if (t == 255) ((unsigned short*)(eb + 3584))[256] = (unsigned short)(exc + c);
    ((float*)(eb + 2560))[t] = rsqrtf((float)(c + 1));
    base[t] = (unsigned)exc;
    __syncthreads();
    for (int i = t; i < ecnt; i += 256) {
        unsigned short v = ep[i];
        unsigned p = atomicAdd(&base[v >> 8], 1u);
        if (p < ECAP2) eb[p] = (unsigned char)(v & 255);
    }
}

// ---- persistent fused kernel: full resident M, 16 waves --------------------

__global__ void __launch_bounds__(TPB) k_fused(
    const float* __restrict__ x, const int* __restrict__ station_ids,
    const float* __restrict__ W1, const float* __restrict__ b1,
    const float* __restrict__ W2, const float* __restrict__ b2,
    const float* __restrict__ fc1W, const float* __restrict__ fc1b,
    const float* __restrict__ fc2W, const float* __restrict__ fc2b,
    const unsigned char* __restrict__ eblob, float* __restrict__ out) {

    __shared__ __align__(16) unsigned char Ms[256 * MROW]; // full M, 520B rows
    __shared__ __align__(16) unsigned char Buf[32 * BROW]; // G1T/H1T, 520B rows
    __shared__ __align__(16) unsigned char El[ECAP2];      // src sorted by dst
    __shared__ __align__(16) float dinvs[256];
    __shared__ __align__(4) unsigned short Rl[260];
    __shared__ float W1s[288];
    __shared__ float sts[512];                             // [8][64] f32
    __shared__ float poolf[64];
    __shared__ float spart[8];
    __shared__ unsigned char stmap[256];
    __shared__ float b1s[32], b2s[64], fc1bs[64], fc2ws[64];
    __shared__ int stids[8];
    __shared__ float fc2bv;

    int t = threadIdx.x;
    int lane = t & 63, wvid = t >> 6;                    // 16 waves
    int m = lane & 15, quad = lane >> 4;

    // ---- persistent staging (once per block) ----
    for (int i = t; i < NFEAT * 32; i += TPB) W1s[i] = W1[i];
    if (t < 32) b1s[t] = b1[t];
    if (t < 64) { b2s[t] = b2[t]; fc1bs[t] = fc1b[t]; fc2ws[t] = fc2W[t]; poolf[t] = 0.f; }
    if (t < 8) { stids[t] = station_ids[t]; spart[t] = 0.f; }
    if (t == 0) fc2bv = fc2b[0];
    if (t < 256) stmap[t] = 255;
    // W2 B-fragments, persistent in registers: w2f[ni] = W2[quad*8+j][ni*16+m]
    short8 w2f[4];
#pragma unroll
    for (int ni = 0; ni < 4; ++ni)
#pragma unroll
        for (int j = 0; j < 8; ++j)
            w2f[ni][j] = (short)f2bbits(W2[(quad * 8 + j) * 64 + ni * 16 + m]);
    // fc1 B-fragments, persistent in registers: wave w holds channel block w&3.
    short8 fc1f[4];
    {
        int ni = wvid & 3;
#pragma unroll
        for (int kt = 0; kt < 4; ++kt)
#pragma unroll
            for (int j = 0; j < 8; ++j)
                fc1f[kt][j] = (short)f2bbits(fc1W[((kt * 4 + quad) * 8 + j) * 64 + ni * 16 + m]);
    }
    __syncthreads();
    if (t < 8) stmap[stids[t] & 255] = (unsigned char)t;

    for (int g = blockIdx.x; g < NGRAPHS; g += NBLK) {

        // ---- P0: stage El / dinvs / Rl from the sort2 blob
        {
            const unsigned char* eb = eblob + (size_t)g * EBSTRIDE;
            const uint4* ev = (const uint4*)eb;                 // 160 units
            const uint4* dv = (const uint4*)(eb + 2560);        // 64 units
            const unsigned int* rv = (const unsigned int*)(eb + 3584); // 129 uints
            for (int i = t; i < 160; i += TPB) ((uint4*)El)[i] = ev[i];
            for (int i = t; i < 64; i += TPB) ((uint4*)dinvs)[i] = dv[i];
            for (int i = t; i < 129; i += TPB) ((unsigned int*)Rl)[i] = rv[i];
        }
        __syncthreads();                                  // B1

        // ---- P1: t<512 full M-build (2 thr/row, self-zeroing) ; t>=512 lin1
        if (t < 512) {
            int d = t >> 1, q = t & 1;
            // zero own 256B half-row, chunk order (i+t)&15 -> all 32 banks busy
            unsigned char* rowp = Ms + d * MROW + q * 256;
            uint4 z = {0u, 0u, 0u, 0u};
#pragma unroll
            for (int i = 0; i < 16; ++i) {
                int cc = (i + t) & 15;
                *(uint4*)(rowp + cc * 16) = z;
            }
            float did = dinvs[d];
            if ((d >> 7) == q)
                *(unsigned short*)(Ms + d * MROW + (((d >> 3) ^ (d & 15)) * 16) + (d & 7) * 2)
                    = f2bbits(did * did);
            int r0 = Rl[d], r1 = Rl[d + 1];
            for (int e = r0; e < r1; ++e) {
                int s = El[e];
                if ((s >> 7) == q) {
                    unsigned short* p =
                        (unsigned short*)(Ms + d * MROW + (((s >> 3) ^ (d & 15)) * 16) + (s & 7) * 2);
                    *p = f2bbits(bfbits(*p) + did * dinvs[s]);
                }
            }
        } else {
            int tt = t - 512;
            int n = tt >> 1, half = tt & 1;
            const float* xr = x + (size_t)(g * NPG + n) * NFEAT;
            float xv[NFEAT];
#pragma unroll
            for (int k = 0; k < NFEAT; ++k) xv[k] = xr[k];
            int c0 = half * 16;
#pragma unroll 4
            for (int ci = 0; ci < 16; ++ci) {
                int c = c0 + ci;
                float acc = 0.f;
#pragma unroll
                for (int k = 0; k < NFEAT; ++k) acc += xv[k] * W1s[k * 32 + c];
                *(unsigned short*)(Buf + c * BROW + (((n >> 3) ^ (c & 15)) * 16) + (n & 7) * 2)
                    = f2bbits(acc);
            }
        }
        __syncthreads();                                  // B2

        // ---- P2: agg1 full (af re-read per kt from LDS; no hoist -> no spill)
        f32x4 acc1[2] = {};
        for (int kt = 0; kt < 8; ++kt) {
            short8 af = *(const short8*)(Ms + (size_t)(wvid * 16 + m) * MROW + (((kt * 4 + quad) ^ m) * 16));
            short8 bf0 = *(const short8*)(Buf + (size_t)m * BROW + (((kt * 4 + quad) ^ m) * 16));
            short8 bf1 = *(const short8*)(Buf + (size_t)(16 + m) * BROW + (((kt * 4 + quad) ^ m) * 16));
            acc1[0] = __builtin_amdgcn_mfma_f32_16x16x32_bf16(af, bf0, acc1[0], 0, 0, 0);
            acc1[1] = __builtin_amdgcn_mfma_f32_16x16x32_bf16(af, bf1, acc1[1], 0, 0, 0);
        }
        __syncthreads();                                  // B3 (all G1T reads done)

        // ---- P2b: relu+bias -> H1T over Buf
#pragma unroll
        for (int ct = 0; ct < 2; ++ct) {
            int ch = ct * 16 + m;
            float bb = b1s[ch];
#pragma unroll
            for (int r = 0; r < 4; ++r) {
                int node = wvid * 16 + quad * 4 + r;
                *(unsigned short*)(Buf + (size_t)ch * BROW + (((node >> 3) ^ (ch & 15)) * 16) + (node & 7) * 2)
                    = f2bbits(fmaxf(acc1[ct][r] + bb, 0.f));
            }
        }
        __syncthreads();                                  // B4

        // ---- P3: agg2 (M resident) -> S2 slots in own dead Ms rows
        {
            f32x4 a2[2] = {};
            for (int kt = 0; kt < 8; ++kt) {
                short8 af = *(const short8*)(Ms + (size_t)(wvid * 16 + m) * MROW + (((kt * 4 + quad) ^ m) * 16));
                short8 bf0 = *(const short8*)(Buf + (size_t)m * BROW + (((kt * 4 + quad) ^ m) * 16));
                short8 bf1 = *(const short8*)(Buf + (size_t)(16 + m) * BROW + (((kt * 4 + quad) ^ m) * 16));
                a2[0] = __builtin_amdgcn_mfma_f32_16x16x32_bf16(af, bf0, a2[0], 0, 0, 0);
                a2[1] = __builtin_amdgcn_mfma_f32_16x16x32_bf16(af, bf1, a2[1], 0, 0, 0);
            }
            // wave wvid's output nodes == its own af rows: safe to overwrite
#pragma unroll
            for (int ct = 0; ct < 2; ++ct) {
                int ch = ct * 16 + m;
                int c8 = ch >> 3;
#pragma unroll
                for (int r = 0; r < 4; ++r) {
                    int node = wvid * 16 + quad * 4 + r;
                    *(unsigned short*)(Ms + (size_t)node * MROW + ((c8 ^ (node & 3)) * 16) + (ch & 7) * 2)
                        = f2bbits(a2[ct][r]);
                }
            }
        }
        __syncthreads();                                  // B5

        // ---- P4: lin2 = relu(S2@W2+b2); pool + stations (W2 in registers)
        {
            int mt = wvid;
            short8 af2 = *(const short8*)(Ms + (size_t)(mt * 16 + m) * MROW + ((quad ^ (m & 3)) * 16));
#pragma unroll
            for (int ni = 0; ni < 4; ++ni) {
                f32x4 c = {};
                c = __builtin_amdgcn_mfma_f32_16x16x32_bf16(af2, w2f[ni], c, 0, 0, 0);
                int ch = ni * 16 + m;
                float bb = b2s[ch];
                float hv[4];
                float p = 0.f;
#pragma unroll
                for (int r = 0; r < 4; ++r) { hv[r] = fmaxf(c[r] + bb, 0.f); p += hv[r]; }
                p += __shfl_down(p, 32);
                p += __shfl_down(p, 16);
                if (quad == 0) atomicAdd(&poolf[ch], p);
#pragma unroll
                for (int r = 0; r < 4; ++r) {
                    int node = mt * 16 + quad * 4 + r;
                    int si = stmap[node];
                    if (si != 255) sts[si * 64 + ch] = hv[r];
                }
            }
        }
        __syncthreads();                                  // B6

        // ---- P6: station MLP, waves 0..3 (ni = wvid), register-resident fc1
        if (wvid < 4) {
            short8 af4[4];
#pragma unroll
            for (int kt = 0; kt < 4; ++kt) {
#pragma unroll
                for (int j = 0; j < 8; ++j) {
                    int k = kt * 32 + quad * 8 + j;
                    float v = 0.f;
                    if (m < 8) v = (k < 64) ? sts[m * 64 + k] : poolf[k - 64] * (1.0f / 256.0f);
                    af4[kt][j] = (short)f2bbits(v);
                }
            }
            f32x4 c = {};
#pragma unroll
            for (int kt = 0; kt < 4; ++kt)
                c = __builtin_amdgcn_mfma_f32_16x16x32_bf16(af4[kt], fc1f[kt], c, 0, 0, 0);
            int ch = wvid * 16 + m;
            float fb = fc1bs[ch], fw = fc2ws[ch];
#pragma unroll
            for (int r = 0; r < 4; ++r) {
                float a = fmaxf(c[r] + fb, 0.f) * fw;
#pragma unroll
                for (int off = 1; off < 16; off <<= 1) a += __shfl_xor(a, off);
                int st = quad * 4 + r;
                if (m == 0 && st < 8) atomicAdd(&spart[st], a);
            }
        }
        __syncthreads();                                  // B7

        // out-write + re-zero (same-thread sequencing; next B1 orders vs reuse)
        if (t < 8) { out[g * 8 + t] = spart[t] + fc2bv; spart[t] = 0.f; }
        if (t >= 64 && t < 128) poolf[t - 64] = 0.f;
    }
}

// ---- launch -----------------------------------------------------------------

extern "C" void kernel_launch(void* const* d_in, const int* in_sizes, int n_in,
                              void* d_out, int out_size, void* d_ws, size_t ws_size,
                              hipStream_t stream) {
    const float* x = (const float*)d_in[0];
    const int* ei = (const int*)d_in[1];
    const int* station_ids = (const int*)d_in[2];
    const float* W1 = (const float*)d_in[3];
    const float* b1 = (const float*)d_in[4];
    const float* W2 = (const float*)d_in[5];
    const float* bias2 = (const float*)d_in[6];
    const float* fc1W = (const float*)d_in[7];
    const float* fc1b = (const float*)d_in[8];
    const float* fc2W = (const float*)d_in[9];
    const float* fc2b = (const float*)d_in[10];
    float* out = (float*)d_out;
    (void)in_sizes; (void)n_in; (void)out_size; (void)ws_size;

    char* ws = (char*)d_ws;
    int* gcnt = (int*)ws;                                     // 64 KiB, stride-16 totals
    unsigned short* gout = (unsigned short*)(ws + 0x10000);   // 5.24 MB
    int* hist = (int*)(ws + 0x510000);                        // 1 MB: [tile][graph]
    unsigned char* eblob = (unsigned char*)(ws + 0x610000);   // 4.7 MB: per-graph blobs

    const int* esrc = ei;
    const int* edst = ei + NEDGES;

    k_hist<<<NTILES, 1024, 0, stream>>>(edst, hist);
    k_scan<<<NGRAPHS, 256, 0, stream>>>(hist, gcnt);
    k_scatter<<<NTILES, 1024, 0, stream>>>(esrc, edst, hist, gout);
    k_sort2<<<NGRAPHS, 256, 0, stream>>>(gcnt, gout, eblob);
    k_fused<<<NBLK, TPB, 0, stream>>>(x, station_ids, W1, b1, W2, bias2,
                                      fc1W, fc1b, fc2W, fc2b, eblob, out);
}

// Round 13
// 160.918 us; speedup vs baseline: 1.1140x; 1.1140x over previous
//
#include <hip/hip_runtime.h>
#include <hip/hip_bf16.h>

// GraphQNetwork: 2x GCNConv (9->32->64, relu) + global mean pool + station MLP.
// Round 26: r20 baseline (61us, spill-free, 512B strides) + register-free fixes
// only. The 520B stride (r21/r24/r25) itself caused the 18.5MB scratch spill
// (64-VGPR allocator pin + shift+add addressing everywhere); the chunk^m
// fragment swizzle already spreads agg b128 reads across all 32 banks, so the
// stride bought nothing. Kept: (1) (i+t)&15 zero ordering (the real conflict
// source: all lanes hitting one 16B slot); (2) blob PREFETCH — El/dinvs/Rl are
// dead after P1, so waves 4..15 stage graph g+NBLK's blob during P6 (waves
// 0..3). P0 and one barrier deleted: 6 barriers/graph. Partition unchanged.

#define NNODES 262144
#define NPG 256
#define NGRAPHS 1024
#define NEDGES 2097152
#define NFEAT 9
#define ECAP2 2560
#define T_EDGES 8192
#define NTILES (NEDGES / T_EDGES)   // 256
#define TPB 1024
#define NBLK 256
#define EBSTRIDE 4608               // per-graph blob stride: El@0, dinvs@2560, Rl@3584

typedef __hip_bfloat16 bf16;
typedef short short8 __attribute__((ext_vector_type(8)));
typedef float f32x4 __attribute__((ext_vector_type(4)));

__device__ __forceinline__ float bfbits(unsigned short u) { return __uint_as_float(((unsigned)u) << 16); }
__device__ __forceinline__ unsigned short f2bbits(float v) { bf16 b = __float2bfloat16(v); return *(unsigned short*)&b; }

// ---- edge partition: deterministic counting sort, no global atomics --------

__global__ void __launch_bounds__(1024) k_hist(const int* __restrict__ dst,
                                               int* __restrict__ hist) {
    __shared__ int cnt[NGRAPHS];
    int t = threadIdx.x;
    cnt[t] = 0;
    __syncthreads();
    const int4* d4 = (const int4*)(dst + blockIdx.x * T_EDGES);
#pragma unroll
    for (int k = 0; k < T_EDGES / 4096; ++k) {
        int4 dv = d4[k * 1024 + t];
        atomicAdd(&cnt[dv.x >> 8], 1);
        atomicAdd(&cnt[dv.y >> 8], 1);
        atomicAdd(&cnt[dv.z >> 8], 1);
        atomicAdd(&cnt[dv.w >> 8], 1);
    }
    __syncthreads();
    hist[blockIdx.x * NGRAPHS + t] = cnt[t];
}

__global__ void __launch_bounds__(256) k_scan(int* __restrict__ hist,
                                              int* __restrict__ gcnt) {
    __shared__ int wsum[4];
    int g = blockIdx.x;
    int t = threadIdx.x;            // tile index
    int lane = t & 63, wv = t >> 6;
    int v = hist[t * NGRAPHS + g];
    int inc = v;
    for (int off = 1; off < 64; off <<= 1) {
        int y = __shfl_up(inc, off);
        if (lane >= off) inc += y;
    }
    if (lane == 63) wsum[wv] = inc;
    __syncthreads();
    int wpre = 0;
#pragma unroll
    for (int w = 0; w < 3; ++w) if (w < wv) wpre += wsum[w];
    int exc = wpre + inc - v;
    hist[t * NGRAPHS + g] = exc;
    if (t == 255) gcnt[g * 16] = exc + v;
}

__global__ void __launch_bounds__(1024) k_scatter(const int* __restrict__ src,
                                                  const int* __restrict__ dst,
                                                  const int* __restrict__ hist,
                                                  unsigned short* __restrict__ gout) {
    __shared__ unsigned short sg[T_EDGES];
    __shared__ unsigned short pay[T_EDGES];
    __shared__ unsigned short spay[T_EDGES];
    __shared__ unsigned short ssg[T_EDGES];
    __shared__ int cnt[NGRAPHS];
    __shared__ int lbase[NGRAPHS];
    __shared__ int gb[NGRAPHS];
    __shared__ int wsum[16];
    int t = threadIdx.x;
    int lane = t & 63, wv = t >> 6;
    int base = blockIdx.x * T_EDGES;
    cnt[t] = 0;
    gb[t] = hist[blockIdx.x * NGRAPHS + t];
    __syncthreads();
    const int4* s4 = (const int4*)(src + base);
    const int4* d4 = (const int4*)(dst + base);
#pragma unroll
    for (int k = 0; k < T_EDGES / 4096; ++k) {
        int idx = k * 1024 + t;
        int4 dv = d4[idx];
        int4 sv = s4[idx];
        int i0 = idx * 4;
        sg[i0]     = (unsigned short)(dv.x >> 8);
        sg[i0 + 1] = (unsigned short)(dv.y >> 8);
        sg[i0 + 2] = (unsigned short)(dv.z >> 8);
        sg[i0 + 3] = (unsigned short)(dv.w >> 8);
        pay[i0]     = (unsigned short)(((dv.x & 255) << 8) | (sv.x & 255));
        pay[i0 + 1] = (unsigned short)(((dv.y & 255) << 8) | (sv.y & 255));
        pay[i0 + 2] = (unsigned short)(((dv.z & 255) << 8) | (sv.z & 255));
        pay[i0 + 3] = (unsigned short)(((dv.w & 255) << 8) | (sv.w & 255));
        atomicAdd(&cnt[dv.x >> 8], 1);
        atomicAdd(&cnt[dv.y >> 8], 1);
        atomicAdd(&cnt[dv.z >> 8], 1);
        atomicAdd(&cnt[dv.w >> 8], 1);
    }
    __syncthreads();
    int c = cnt[t];
    int inc = c;
    for (int off = 1; off < 64; off <<= 1) {
        int y = __shfl_up(inc, off);
        if (lane >= off) inc += y;
    }
    if (lane == 63) wsum[wv] = inc;
    __syncthreads();
    int wpre = 0;
    for (int w = 0; w < wv; ++w) wpre += wsum[w];
    lbase[t] = wpre + inc - c;
    cnt[t] = 0;
    __syncthreads();
#pragma unroll
    for (int k = 0; k < T_EDGES / 1024; ++k) {
        int i = k * 1024 + t;
        int g = sg[i];
        int p = lbase[g] + atomicAdd(&cnt[g], 1);
        spay[p] = pay[i];
        ssg[p] = (unsigned short)g;
    }
    __syncthreads();
#pragma unroll
    for (int k = 0; k < T_EDGES / 1024; ++k) {
        int p = k * 1024 + t;
        int g = ssg[p];
        int off = gb[g] + (p - lbase[g]);
        if (off < ECAP2) gout[(size_t)g * ECAP2 + off] = spay[p];
    }
}

// D: per-graph dst-sort: El (src sorted by dst), Rl run table, dinvs.
__global__ void __launch_bounds__(256) k_sort2(const int* __restrict__ gcnt,
                                               const unsigned short* __restrict__ gout,
                                               unsigned char* __restrict__ eblob) {
    __shared__ unsigned short ep[ECAP2];
    __shared__ unsigned int cnt[256];
    __shared__ unsigned int base[256];
    __shared__ int wsum[4];
    int g = blockIdx.x;
    int t = threadIdx.x;
    int lane = t & 63, wv = t >> 6;
    int ecnt = min(gcnt[g * 16], ECAP2);
    cnt[t] = 0;
    {
        const uint4* gev = (const uint4*)(gout + (size_t)g * ECAP2);
        uint4* epv = (uint4*)ep;
        for (int i = t; i < ECAP2 / 8; i += 256) epv[i] = gev[i];
    }
    __syncthreads();
    for (int i = t; i < ecnt; i += 256) atomicAdd(&cnt[ep[i] >> 8], 1u);
    __syncthreads();
    int c = (int)cnt[t];
    int inc = c;
    for (int off = 1; off < 64; off <<= 1) {
        int y = __shfl_up(inc, off);
        if (lane >= off) inc += y;
    }
    if (lane == 63) wsum[wv] = inc;
    __syncthreads();
    int wpre = 0;
    for (int w = 0; w < wv; ++w) wpre += wsum[w];
    int exc = wpre + inc - c;
    unsigned char* eb = eblob + (size_t)g * EBSTRIDE;
    ((unsigned short*)(eb + 3584))[t] = (unsigned short)exc;
    if (t == 255) ((unsigned short*)(eb + 3584))[256] = (unsigned short)(exc + c);
    ((float*)(eb + 2560))[t] = rsqrtf((float)(c + 1));
    base[t] = (unsigned)exc;
    __syncthreads();
    for (int i = t; i < ecnt; i += 256) {
        unsigned short v = ep[i];
        unsigned p = atomicAdd(&base[v >> 8], 1u);
        if (p < ECAP2) eb[p] = (unsigned char)(v & 255);
    }
}

// ---- persistent fused kernel: full resident M, 16 waves --------------------

__global__ void __launch_bounds__(TPB) k_fused(
    const float* __restrict__ x, const int* __restrict__ station_ids,
    const float* __restrict__ W1, const float* __restrict__ b1,
    const float* __restrict__ W2, const float* __restrict__ b2,
    const float* __restrict__ fc1W, const float* __restrict__ fc1b,
    const float* __restrict__ fc2W, const float* __restrict__ fc2b,
    const unsigned char* __restrict__ eblob, float* __restrict__ out) {

    __shared__ __align__(16) unsigned char Ms[131072];   // full M: 256 x 512 B
    __shared__ __align__(16) unsigned char Buf[16384];   // G1T then H1T [32][256] swz
    __shared__ __align__(16) unsigned char El[ECAP2];    // src sorted by dst
    __shared__ __align__(16) float dinvs[256];
    __shared__ __align__(4) unsigned short Rl[260];
    __shared__ float W1s[288];
    __shared__ float sts[512];                           // [8][64] f32
    __shared__ float poolf[64];
    __shared__ float spart[8];
    __shared__ unsigned char stmap[256];
    __shared__ float b1s[32], b2s[64], fc1bs[64], fc2ws[64];
    __shared__ int stids[8];
    __shared__ float fc2bv;

    int t = threadIdx.x;
    int lane = t & 63, wvid = t >> 6;                    // 16 waves
    int m = lane & 15, quad = lane >> 4;

    // ---- persistent staging (once per block) ----
    for (int i = t; i < NFEAT * 32; i += TPB) W1s[i] = W1[i];
    if (t < 32) b1s[t] = b1[t];
    if (t < 64) { b2s[t] = b2[t]; fc1bs[t] = fc1b[t]; fc2ws[t] = fc2W[t]; poolf[t] = 0.f; }
    if (t < 8) { stids[t] = station_ids[t]; spart[t] = 0.f; }
    if (t == 0) fc2bv = fc2b[0];
    if (t < 256) stmap[t] = 255;
    // W2 B-fragments, persistent in registers: w2f[ni] = W2[quad*8+j][ni*16+m]
    short8 w2f[4];
#pragma unroll
    for (int ni = 0; ni < 4; ++ni)
#pragma unroll
        for (int j = 0; j < 8; ++j)
            w2f[ni][j] = (short)f2bbits(W2[(quad * 8 + j) * 64 + ni * 16 + m]);
    // fc1 B-fragments, persistent in registers: wave w holds channel block w&3.
    short8 fc1f[4];
    {
        int ni = wvid & 3;
#pragma unroll
        for (int kt = 0; kt < 4; ++kt)
#pragma unroll
            for (int j = 0; j < 8; ++j)
                fc1f[kt][j] = (short)f2bbits(fc1W[((kt * 4 + quad) * 8 + j) * 64 + ni * 16 + m]);
    }
    // ---- prologue: stage first graph's blob (El/dinvs/Rl) ----
    {
        const unsigned char* eb = eblob + (size_t)blockIdx.x * EBSTRIDE;
        for (int i = t; i < 160; i += TPB) ((uint4*)El)[i] = ((const uint4*)eb)[i];
        for (int i = t; i < 64; i += TPB) ((uint4*)dinvs)[i] = ((const uint4*)(eb + 2560))[i];
        for (int i = t; i < 129; i += TPB) ((unsigned int*)Rl)[i] = ((const unsigned int*)(eb + 3584))[i];
    }
    __syncthreads();
    if (t < 8) stmap[stids[t] & 255] = (unsigned char)t;

    for (int g = blockIdx.x; g < NGRAPHS; g += NBLK) {

        // ---- P1: t<512 full M-build (2 thr/row, self-zeroing) ; t>=512 lin1
        if (t < 512) {
            int d = t >> 1, q = t & 1;
            // zero own 256B half-row, chunk order (i+t)&15 -> banks spread
            unsigned char* rowp = Ms + d * 512 + q * 256;
            uint4 z = {0u, 0u, 0u, 0u};
#pragma unroll
            for (int i = 0; i < 16; ++i) {
                int cc = (i + t) & 15;
                *(uint4*)(rowp + cc * 16) = z;
            }
            float did = dinvs[d];
            if ((d >> 7) == q)
                *(unsigned short*)(Ms + d * 512 + (((d >> 3) ^ (d & 15)) * 16) + (d & 7) * 2)
                    = f2bbits(did * did);
            int r0 = Rl[d], r1 = Rl[d + 1];
            for (int e = r0; e < r1; ++e) {
                int s = El[e];
                if ((s >> 7) == q) {
                    unsigned short* p =
                        (unsigned short*)(Ms + d * 512 + (((s >> 3) ^ (d & 15)) * 16) + (s & 7) * 2);
                    *p = f2bbits(bfbits(*p) + did * dinvs[s]);
                }
            }
        } else {
            int tt = t - 512;
            int n = tt >> 1, half = tt & 1;
            const float* xr = x + (size_t)(g * NPG + n) * NFEAT;
            float xv[NFEAT];
#pragma unroll
            for (int k = 0; k < NFEAT; ++k) xv[k] = xr[k];
            int c0 = half * 16;
#pragma unroll 4
            for (int ci = 0; ci < 16; ++ci) {
                int c = c0 + ci;
                float acc = 0.f;
#pragma unroll
                for (int k = 0; k < NFEAT; ++k) acc += xv[k] * W1s[k * 32 + c];
                *(unsigned short*)(Buf + c * 512 + (((n >> 3) ^ (c & 15)) * 16) + (n & 7) * 2)
                    = f2bbits(acc);
            }
        }
        __syncthreads();                                  // B1

        // ---- P2: agg1 full -> registers (wave = 16-node row tile, 2 ch tiles)
        f32x4 acc1[2] = {};
        for (int kt = 0; kt < 8; ++kt) {
            short8 af = *(const short8*)(Ms + (size_t)(wvid * 16 + m) * 512 + (((kt * 4 + quad) ^ m) * 16));
            short8 bf0 = *(const short8*)(Buf + (size_t)m * 512 + (((kt * 4 + quad) ^ m) * 16));
            short8 bf1 = *(const short8*)(Buf + (size_t)(16 + m) * 512 + (((kt * 4 + quad) ^ m) * 16));
            acc1[0] = __builtin_amdgcn_mfma_f32_16x16x32_bf16(af, bf0, acc1[0], 0, 0, 0);
            acc1[1] = __builtin_amdgcn_mfma_f32_16x16x32_bf16(af, bf1, acc1[1], 0, 0, 0);
        }
        __syncthreads();                                  // B2 (all G1T reads done)

        // ---- P2b: relu+bias -> H1T over Buf
#pragma unroll
        for (int ct = 0; ct < 2; ++ct) {
            int ch = ct * 16 + m;
            float bb = b1s[ch];
#pragma unroll
            for (int r = 0; r < 4; ++r) {
                int node = wvid * 16 + quad * 4 + r;
                *(unsigned short*)(Buf + (size_t)ch * 512 + (((node >> 3) ^ (ch & 15)) * 16) + (node & 7) * 2)
                    = f2bbits(fmaxf(acc1[ct][r] + bb, 0.f));
            }
        }
        __syncthreads();                                  // B3

        // ---- P3: agg2 (M resident) -> S2 slots in own dead Ms rows
        {
            f32x4 a2[2] = {};
            for (int kt = 0; kt < 8; ++kt) {
                short8 af = *(const short8*)(Ms + (size_t)(wvid * 16 + m) * 512 + (((kt * 4 + quad) ^ m) * 16));
                short8 bf0 = *(const short8*)(Buf + (size_t)m * 512 + (((kt * 4 + quad) ^ m) * 16));
                short8 bf1 = *(const short8*)(Buf + (size_t)(16 + m) * 512 + (((kt * 4 + quad) ^ m) * 16));
                a2[0] = __builtin_amdgcn_mfma_f32_16x16x32_bf16(af, bf0, a2[0], 0, 0, 0);
                a2[1] = __builtin_amdgcn_mfma_f32_16x16x32_bf16(af, bf1, a2[1], 0, 0, 0);
            }
            // wave wvid's output nodes == its own af rows: safe to overwrite
#pragma unroll
            for (int ct = 0; ct < 2; ++ct) {
                int ch = ct * 16 + m;
                int c8 = ch >> 3;
#pragma unroll
                for (int r = 0; r < 4; ++r) {
                    int node = wvid * 16 + quad * 4 + r;
                    *(unsigned short*)(Ms + (size_t)node * 512 + ((c8 ^ (node & 3)) * 16) + (ch & 7) * 2)
                        = f2bbits(a2[ct][r]);
                }
            }
        }
        __syncthreads();                                  // B4

        // ---- P4: lin2 = relu(S2@W2+b2); pool + stations (W2 in registers)
        {
            int mt = wvid;
            short8 af2 = *(const short8*)(Ms + (size_t)(mt * 16 + m) * 512 + ((quad ^ (m & 3)) * 16));
#pragma unroll
            for (int ni = 0; ni < 4; ++ni) {
                f32x4 c = {};
                c = __builtin_amdgcn_mfma_f32_16x16x32_bf16(af2, w2f[ni], c, 0, 0, 0);
                int ch = ni * 16 + m;
                float bb = b2s[ch];
                float hv[4];
                float p = 0.f;
#pragma unroll
                for (int r = 0; r < 4; ++r) { hv[r] = fmaxf(c[r] + bb, 0.f); p += hv[r]; }
                p += __shfl_down(p, 32);
                p += __shfl_down(p, 16);
                if (quad == 0) atomicAdd(&poolf[ch], p);
#pragma unroll
                for (int r = 0; r < 4; ++r) {
                    int node = mt * 16 + quad * 4 + r;
                    int si = stmap[node];
                    if (si != 255) sts[si * 64 + ch] = hv[r];
                }
            }
        }
        __syncthreads();                                  // B5

        // ---- P6: station MLP on waves 0..3 ; waves 4..15 prefetch next blob
        if (wvid < 4) {
            short8 af4[4];
#pragma unroll
            for (int kt = 0; kt < 4; ++kt) {
#pragma unroll
                for (int j = 0; j < 8; ++j) {
                    int k = kt * 32 + quad * 8 + j;
                    float v = 0.f;
                    if (m < 8) v = (k < 64) ? sts[m * 64 + k] : poolf[k - 64] * (1.0f / 256.0f);
                    af4[kt][j] = (short)f2bbits(v);
                }
            }
            f32x4 c = {};
#pragma unroll
            for (int kt = 0; kt < 4; ++kt)
                c = __builtin_amdgcn_mfma_f32_16x16x32_bf16(af4[kt], fc1f[kt], c, 0, 0, 0);
            int ch = wvid * 16 + m;
            float fb = fc1bs[ch], fw = fc2ws[ch];
#pragma unroll
            for (int r = 0; r < 4; ++r) {
                float a = fmaxf(c[r] + fb, 0.f) * fw;
#pragma unroll
                for (int off = 1; off < 16; off <<= 1) a += __shfl_xor(a, off);
                int st = quad * 4 + r;
                if (m == 0 && st < 8) atomicAdd(&spart[st], a);
            }
        } else {
            // El/dinvs/Rl are dead after P1: stage graph g+NBLK in place.
            int gn = g + NBLK;
            if (gn < NGRAPHS) {
                const unsigned char* eb = eblob + (size_t)gn * EBSTRIDE;
                int ts = t - 256;                        // 0..767
                for (int i = ts; i < 160; i += 768) ((uint4*)El)[i] = ((const uint4*)eb)[i];
                for (int i = ts; i < 64; i += 768) ((uint4*)dinvs)[i] = ((const uint4*)(eb + 2560))[i];
                for (int i = ts; i < 129; i += 768) ((unsigned int*)Rl)[i] = ((const unsigned int*)(eb + 3584))[i];
            }
        }
        __syncthreads();                                  // B6

        // out-write + re-zero (same-thread sequencing; next B1 orders vs reuse)
        if (t < 8) { out[g * 8 + t] = spart[t] + fc2bv; spart[t] = 0.f; }
        if (t >= 64 && t < 128) poolf[t - 64] = 0.f;
    }
}

// ---- launch -----------------------------------------------------------------

extern "C" void kernel_launch(void* const* d_in, const int* in_sizes, int n_in,
                              void* d_out, int out_size, void* d_ws, size_t ws_size,
                              hipStream_t stream) {
    const float* x = (const float*)d_in[0];
    const int* ei = (const int*)d_in[1];
    const int* station_ids = (const int*)d_in[2];
    const float* W1 = (const float*)d_in[3];
    const float* b1 = (const float*)d_in[4];
    const float* W2 = (const float*)d_in[5];
    const float* bias2 = (const float*)d_in[6];
    const float* fc1W = (const float*)d_in[7];
    const float* fc1b = (const float*)d_in[8];
    const float* fc2W = (const float*)d_in[9];
    const float* fc2b = (const float*)d_in[10];
    float* out = (float*)d_out;
    (void)in_sizes; (void)n_in; (void)out_size; (void)ws_size;

    char* ws = (char*)d_ws;
    int* gcnt = (int*)ws;                                     // 64 KiB, stride-16 totals
    unsigned short* gout = (unsigned short*)(ws + 0x10000);   // 5.24 MB
    int* hist = (int*)(ws + 0x510000);                        // 1 MB: [tile][graph]
    unsigned char* eblob = (unsigned char*)(ws + 0x610000);   // 4.7 MB: per-graph blobs

    const int* esrc = ei;
    const int* edst = ei + NEDGES;

    k_hist<<<NTILES, 1024, 0, stream>>>(edst, hist);
    k_scan<<<NGRAPHS, 256, 0, stream>>>(hist, gcnt);
    k_scatter<<<NTILES, 1024, 0, stream>>>(esrc, edst, hist, gout);
    k_sort2<<<NGRAPHS, 256, 0, stream>>>(gcnt, gout, eblob);
    k_fused<<<NBLK, TPB, 0, stream>>>(x, station_ids, W1, b1, W2, bias2,
                                      fc1W, fc1b, fc2W, fc2b, eblob, out);
}